// Round 9
// baseline (391.800 us; speedup 1.0000x reference)
//
#include <hip/hip_runtime.h>

typedef __bf16 bf16x8 __attribute__((ext_vector_type(8)));
typedef float f32x4 __attribute__((ext_vector_type(4)));

__device__ __forceinline__ unsigned short f2bf(float f) {
    unsigned int u = __builtin_bit_cast(unsigned int, f);
    u += 0x7fffu + ((u >> 16) & 1u);
    return (unsigned short)(u >> 16);
}
__device__ __forceinline__ float bf2f(unsigned short u) {
    return __builtin_bit_cast(float, (unsigned)u << 16);
}

// XOR swizzle for 1024B-row LDS tiles: byte ^= ((row&7)<<4)
__device__ __forceinline__ unsigned swz1k(unsigned byte) {
    return byte ^ ((byte >> 6) & 0x70u);
}

// Raw barrier: LDS-visibility only; does NOT drain vmcnt.
__device__ __forceinline__ void bar_lgkm() {
    asm volatile("s_waitcnt lgkmcnt(0)\n\ts_barrier" ::: "memory");
}

// ---------------- K1: Pc[kc][j][t] = M[kc*32+t][j], M = Wq^T Wk  (bf16)
// plus Wv -> bf16 copy.
__global__ __launch_bounds__(256) void prep_kernel(
    const float* __restrict__ Wq, const float* __restrict__ Wk,
    const float* __restrict__ Wv, unsigned short* __restrict__ Pc,
    unsigned short* __restrict__ Wvb)
{
    int b = blockIdx.x;
    if (b < 1024) {
        int j0 = (b >> 4) * 8;
        int kc = b & 15;
        int jloc = threadIdx.x >> 5;
        int t = threadIdx.x & 31;
        int j = j0 + jloc, d = kc * 32 + t;
        float acc = 0.f;
        #pragma unroll 8
        for (int e = 0; e < 512; ++e)
            acc = fmaf(Wk[e * 512 + j], Wq[e * 512 + d], acc);
        Pc[((kc * 512) + j) * 32 + t] = f2bf(acc);
    } else {
        int i = (b - 1024) * 256 + (int)threadIdx.x;
        Wvb[i] = f2bf(Wv[i]);
    }
}

// issue H column-quarter q: 4 float4/thread.
__device__ __forceinline__ void issue_quarter(int q, int tid, const float4* hsrc, float4 (&hq)[4]) {
    #pragma unroll
    for (int r = 0; r < 4; ++r) {
        int flat = r * 512 + tid;
        hq[r] = hsrc[(flat >> 5) * 128 + q * 32 + (flat & 31)];
    }
}

// convert quarter q -> bf16 swizzled HBF (consumes hq)
__device__ __forceinline__ void convert_quarter(int q, int tid, char* HBF, float4 (&hq)[4]) {
    #pragma unroll
    for (int r = 0; r < 4; ++r) {
        int flat = r * 512 + tid;
        int row = flat >> 5, ch = flat & 31;
        ushort4 bv;
        bv.x = f2bf(hq[r].x); bv.y = f2bf(hq[r].y);
        bv.z = f2bf(hq[r].z); bv.w = f2bf(hq[r].w);
        *(ushort4*)(HBF + swz1k((unsigned)row * 1024u + (unsigned)(q * 32 + ch) * 8u)) = bv;
    }
}

// GEMM over kc = kcbase..kcbase+3 with 3-deep rolling Pc prefetch.
template<bool PREF>
__device__ __forceinline__ void gemm_quarter(
    int kcbase, int tid, int rl, int kg,
    const unsigned short* bptr, char* HBF,
    bf16x8 (&st0)[4], bf16x8 (&st1)[4], bf16x8 (&st2)[4],
    f32x4 (&acc)[4][4],
    float4 (&hq)[4], const float4* hsrc, int hq_q)
{
    #pragma unroll
    for (int k = 0; k < 4; ++k) {
        const int kc = kcbase + k;
        bf16x8 bn[4];
        if (kc + 3 < 16) {
            #pragma unroll
            for (int jj = 0; jj < 4; ++jj)
                bn[jj] = *(const bf16x8*)(bptr + (kc + 3) * 16384 + jj * 512);
        }
        if (PREF && k == 0) {
            __builtin_amdgcn_sched_barrier(0);
            issue_quarter(hq_q, tid, hsrc, hq);
            __builtin_amdgcn_sched_barrier(0);
        }
        bf16x8 a[4];
        #pragma unroll
        for (int i = 0; i < 4; ++i) {
            unsigned off = (unsigned)(i * 16 + rl) * 1024u + (unsigned)kc * 64u + (unsigned)kg * 16u;
            a[i] = *(bf16x8*)(HBF + swz1k(off));
        }
        #pragma unroll
        for (int i = 0; i < 4; ++i)
            #pragma unroll
            for (int jj = 0; jj < 4; ++jj)
                acc[i][jj] = __builtin_amdgcn_mfma_f32_16x16x32_bf16(a[i], st0[jj], acc[i][jj], 0, 0, 0);
        #pragma unroll
        for (int jj = 0; jj < 4; ++jj) { st0[jj] = st1[jj]; st1[jj] = st2[jj]; st2[jj] = bn[jj]; }
    }
}

// ---------------- K2: fused main kernel. V=0: full/real. V=1: ablation —
// convert+GEMM+TBF only, phases stubbed with a keep-alive scratch write;
// H addressing wrapped so grid can exceed 2048.
template<int V>
__global__ __launch_bounds__(512, 1) void attn_main_kernel(
    const float* __restrict__ H, const float* __restrict__ F,
    const unsigned short* __restrict__ Pc,
    float* __restrict__ out, unsigned short* __restrict__ g_ws,
    float* __restrict__ scratch)
{
    extern __shared__ char smem[];
    char* HBF = smem;                        // 64 rows x 1024B, swizzled (64 KB)
    char* TBF = smem + 65536;                // 64 KB
    float* wbuf = (float*)(smem + 131072);   // [4][16]
    float* FL   = (float*)(smem + 131328);   // [64]
    float* LFL  = (float*)(smem + 131584);   // [64]

    const int tid = threadIdx.x;
    const int wv = tid >> 6;
    const int ln = tid & 63;
    const int rl = ln & 15;
    const int kg = ln >> 4;
    const int blk = (V == 0) ? blockIdx.x : (blockIdx.x & 2047);
    const long long gr0 = (long long)blk * 64;
    const float4* hsrc = (const float4*)(H + gr0 * 512);

    float fval = 0.f;
    if (V == 0 && tid < 64) fval = F[blk * 64 + tid];

    float4 hqA[4], hqB[4];
    issue_quarter(0, tid, hsrc, hqA);

    const unsigned short* bptr = Pc + ((wv * 64 + rl) * 32 + kg * 8);
    bf16x8 st0[4], st1[4], st2[4];
    #pragma unroll
    for (int jj = 0; jj < 4; ++jj) st0[jj] = *(const bf16x8*)(bptr + 0 * 16384 + jj * 512);
    #pragma unroll
    for (int jj = 0; jj < 4; ++jj) st1[jj] = *(const bf16x8*)(bptr + 1 * 16384 + jj * 512);
    #pragma unroll
    for (int jj = 0; jj < 4; ++jj) st2[jj] = *(const bf16x8*)(bptr + 2 * 16384 + jj * 512);

    issue_quarter(1, tid, hsrc, hqB);

    if (V == 0 && tid < 64) {
        FL[tid] = fval;
        LFL[tid] = logf(fval + 1e-8f);
    }

    f32x4 acc[4][4];
    #pragma unroll
    for (int i = 0; i < 4; ++i)
        #pragma unroll
        for (int jj = 0; jj < 4; ++jj)
            acc[i][jj] = f32x4{0.f, 0.f, 0.f, 0.f};

    convert_quarter(0, tid, HBF, hqA);
    bar_lgkm();
    gemm_quarter<false>(0, tid, rl, kg, bptr, HBF, st0, st1, st2, acc, hqA, hsrc, 0);
    convert_quarter(1, tid, HBF, hqB);
    bar_lgkm();
    gemm_quarter<true >(4, tid, rl, kg, bptr, HBF, st0, st1, st2, acc, hqA, hsrc, 2);
    convert_quarter(2, tid, HBF, hqA);
    bar_lgkm();
    gemm_quarter<true >(8, tid, rl, kg, bptr, HBF, st0, st1, st2, acc, hqB, hsrc, 3);
    convert_quarter(3, tid, HBF, hqB);
    bar_lgkm();
    gemm_quarter<false>(12, tid, rl, kg, bptr, HBF, st0, st1, st2, acc, hqA, hsrc, 0);

    // write T (bf16, swizzled rows) into TBF
    #pragma unroll
    for (int i = 0; i < 4; ++i)
        #pragma unroll
        for (int jj = 0; jj < 4; ++jj)
            #pragma unroll
            for (int p = 0; p < 4; ++p) {
                unsigned row = (unsigned)(i * 16 + kg * 4 + p);
                unsigned col = (unsigned)(wv * 64 + jj * 16 + rl);
                *(unsigned short*)(TBF + swz1k(row * 1024u + col * 2u)) = f2bf(acc[i][jj][p]);
            }
    bar_lgkm();   // TBF ready

    if (V == 1) {
        // ---- ablation stub: keep TBF/HBF live via real reads + scratch store
        unsigned short t0 = *(unsigned short*)(TBF + ((unsigned)(tid * 130) & 65534u));
        unsigned short h0 = *(unsigned short*)(HBF + ((unsigned)(tid * 130) & 65534u));
        scratch[(blockIdx.x & 511) * 512 + tid] = bf2f(t0) + bf2f(h0);
        return;
    }

    // ---- phase 3: waves 0-3: scores+softmax+w ; waves 4-7: residual pool
    if (wv < 4) {
        f32x4 sc0 = f32x4{0.f,0.f,0.f,0.f}, sc1 = sc0, sc2 = sc0, sc3 = sc0;
        __builtin_amdgcn_s_setprio(1);
        #pragma unroll
        for (int kc = 0; kc < 16; ++kc) {
            unsigned off = (unsigned)(wv * 16 + rl) * 1024u + (unsigned)kc * 64u + (unsigned)kg * 16u;
            bf16x8 aT = *(bf16x8*)(TBF + swz1k(off));
            bf16x8 bH = *(bf16x8*)(HBF + swz1k(off));   // H rows as B == H^T
            if ((kc & 3) == 0) sc0 = __builtin_amdgcn_mfma_f32_16x16x32_bf16(aT, bH, sc0, 0, 0, 0);
            else if ((kc & 3) == 1) sc1 = __builtin_amdgcn_mfma_f32_16x16x32_bf16(aT, bH, sc1, 0, 0, 0);
            else if ((kc & 3) == 2) sc2 = __builtin_amdgcn_mfma_f32_16x16x32_bf16(aT, bH, sc2, 0, 0, 0);
            else sc3 = __builtin_amdgcn_mfma_f32_16x16x32_bf16(aT, bH, sc3, 0, 0, 0);
        }
        __builtin_amdgcn_s_setprio(0);
        f32x4 sc;
        #pragma unroll
        for (int p = 0; p < 4; ++p) sc[p] = (sc0[p] + sc1[p]) + (sc2[p] + sc3[p]);

        float bias = LFL[wv * 16 + rl];
        float alpha[4];
        #pragma unroll
        for (int p = 0; p < 4; ++p) {
            float s = sc[p] * 0.044194173824159216f + bias;  // 1/sqrt(512)
            float m = s;
            m = fmaxf(m, __shfl_xor(m, 8));
            m = fmaxf(m, __shfl_xor(m, 4));
            m = fmaxf(m, __shfl_xor(m, 2));
            m = fmaxf(m, __shfl_xor(m, 1));
            float e = expf(s - m);
            float sum = e;
            sum += __shfl_xor(sum, 8);
            sum += __shfl_xor(sum, 4);
            sum += __shfl_xor(sum, 2);
            sum += __shfl_xor(sum, 1);
            alpha[p] = e / sum;
        }
        float part = 0.f;
        #pragma unroll
        for (int p = 0; p < 4; ++p) part += FL[wv * 16 + kg * 4 + p] * alpha[p];
        part += __shfl_xor(part, 16);
        part += __shfl_xor(part, 32);
        if (ln < 16) wbuf[wv * 16 + ln] = part;
    } else {
        // residual F-pool, conflict-free: lane stride 4B, 4 column passes
        int bb = wv - 4;
        const long long Bg = (long long)blk * 4 + bb;
        #pragma unroll
        for (int pass = 0; pass < 4; ++pass) {
            float a0 = 0.f, a1 = 0.f;
            #pragma unroll
            for (int k = 0; k < 16; ++k) {
                unsigned off = (unsigned)(bb * 16 + k) * 1024u + (unsigned)(pass * 256 + ln * 4);
                ushort2 h = *(ushort2*)(HBF + swz1k(off));
                float fk = FL[bb * 16 + k];
                a0 = fmaf(fk, bf2f(h.x), a0); a1 = fmaf(fk, bf2f(h.y), a1);
            }
            float2 o; o.x = a0; o.y = a1;
            *(float2*)(out + Bg * 512 + pass * 128 + ln * 2) = o;
        }
    }
    bar_lgkm();   // wbuf ready

    // ---- phase 4: g (bf16). 8 waves = 4 batches x 2 d-halves, from LDS.
    {
        int bb = wv >> 1, dh = wv & 1;
        const long long Bg = (long long)blk * 4 + bb;
        int d0 = dh * 256 + ln * 4;
        float g[4];
        #pragma unroll
        for (int q = 0; q < 4; ++q) g[q] = 0.f;
        #pragma unroll
        for (int k = 0; k < 16; ++k) {
            unsigned off = (unsigned)(bb * 16 + k) * 1024u + (unsigned)d0 * 2u;
            ushort4 h = *(ushort4*)(HBF + swz1k(off));
            float wk = wbuf[bb * 16 + k];
            g[0] = fmaf(wk, bf2f(h.x), g[0]); g[1] = fmaf(wk, bf2f(h.y), g[1]);
            g[2] = fmaf(wk, bf2f(h.z), g[2]); g[3] = fmaf(wk, bf2f(h.w), g[3]);
        }
        ushort4 g4; g4.x = f2bf(g[0]); g4.y = f2bf(g[1]); g4.z = f2bf(g[2]); g4.w = f2bf(g[3]);
        *(ushort4*)(g_ws + Bg * 512 + d0) = g4;
    }
}

// ---------------- K3: out += g @ Wv^T   (8192x512 @ 512x512, bf16 MFMA)
__global__ __launch_bounds__(256) void out_gemm_kernel(
    const unsigned short* __restrict__ g_ws,
    const unsigned short* __restrict__ Wvb,
    float* __restrict__ out)
{
    extern __shared__ char smem[];  // 32 KB: 32 rows x 1024B, swizzled
    const int tid = threadIdx.x;
    const int wv = tid >> 6, ln = tid & 63;
    const int rl = ln & 15, kg = ln >> 4;
    const long long r0 = (long long)blockIdx.x * 32;
    {
        const uint4* src = (const uint4*)(g_ws + r0 * 512);
        #pragma unroll
        for (int q = 0; q < 8; ++q) {
            int idx = q * 256 + tid;
            *(uint4*)(smem + swz1k((unsigned)idx * 16u)) = src[idx];
        }
    }
    __syncthreads();
    f32x4 acc[2][8];
    #pragma unroll
    for (int i = 0; i < 2; ++i)
        #pragma unroll
        for (int jj = 0; jj < 8; ++jj)
            acc[i][jj] = f32x4{0.f, 0.f, 0.f, 0.f};
    for (int kc = 0; kc < 16; ++kc) {
        bf16x8 a[2];
        #pragma unroll
        for (int i = 0; i < 2; ++i) {
            unsigned off = (unsigned)(i * 16 + rl) * 1024u + (unsigned)kc * 64u + (unsigned)kg * 16u;
            a[i] = *(bf16x8*)(smem + swz1k(off));
        }
        bf16x8 bfr[8];
        #pragma unroll
        for (int jj = 0; jj < 8; ++jj) {
            int n = wv * 128 + jj * 16 + rl;
            bfr[jj] = *(const bf16x8*)(Wvb + n * 512 + kc * 32 + kg * 8);
        }
        #pragma unroll
        for (int i = 0; i < 2; ++i)
            #pragma unroll
            for (int jj = 0; jj < 8; ++jj)
                acc[i][jj] = __builtin_amdgcn_mfma_f32_16x16x32_bf16(a[i], bfr[jj], acc[i][jj], 0, 0, 0);
    }
    #pragma unroll
    for (int i = 0; i < 2; ++i)
        #pragma unroll
        for (int jj = 0; jj < 8; ++jj)
            #pragma unroll
            for (int p = 0; p < 4; ++p) {
                int row = i * 16 + kg * 4 + p;
                int col = wv * 128 + jj * 16 + rl;
                out[(r0 + row) * 512 + col] += acc[i][jj][p];
            }
}

extern "C" void kernel_launch(void* const* d_in, const int* in_sizes, int n_in,
                              void* d_out, int out_size, void* d_ws, size_t ws_size,
                              hipStream_t stream)
{
    const float* H  = (const float*)d_in[0];
    const float* F  = (const float*)d_in[1];
    const float* Wq = (const float*)d_in[2];
    const float* Wk = (const float*)d_in[3];
    const float* Wv = (const float*)d_in[4];
    float* out = (float*)d_out;

    unsigned short* Pc  = (unsigned short*)d_ws;       // 16*512*32   = 262144 bf16
    unsigned short* Wvb = Pc + 262144;                 // 512*512     = 262144 bf16
    unsigned short* g   = Wvb + 262144;                // 8192*512    = 4194304 bf16
    float* scratch = (float*)g;                        // reused AFTER K3 consumed g
    (void)in_sizes; (void)n_in; (void)out_size; (void)ws_size;

    prep_kernel<<<dim3(2048), dim3(256), 0, stream>>>(Wq, Wk, Wv, Pc, Wvb);
    attn_main_kernel<0><<<dim3(2048), dim3(512), 131840, stream>>>(H, F, Pc, out, g, scratch);
    out_gemm_kernel<<<dim3(256), dim3(256), 32768, stream>>>(g, Wvb, out);
    // ---- diagnostic ablation (scratch-only writes; 2x grid so it tops the
    // rocprof table; removed next round)
    attn_main_kernel<1><<<dim3(4096), dim3(512), 131840, stream>>>(H, F, Pc, out, g, scratch);
}

// Round 10
// 215.666 us; speedup vs baseline: 1.8167x; 1.8167x over previous
//
#include <hip/hip_runtime.h>

typedef __bf16 bf16x8 __attribute__((ext_vector_type(8)));
typedef float f32x4 __attribute__((ext_vector_type(4)));

__device__ __forceinline__ unsigned short f2bf(float f) {
    unsigned int u = __builtin_bit_cast(unsigned int, f);
    u += 0x7fffu + ((u >> 16) & 1u);
    return (unsigned short)(u >> 16);
}
__device__ __forceinline__ float bf2f(unsigned short u) {
    return __builtin_bit_cast(float, (unsigned)u << 16);
}

// XOR swizzle for 1024B-row LDS tiles: byte ^= ((row&7)<<4)
__device__ __forceinline__ unsigned swz1k(unsigned byte) {
    return byte ^ ((byte >> 6) & 0x70u);
}

// Raw barrier: LDS-visibility only; does NOT drain vmcnt.
__device__ __forceinline__ void bar_lgkm() {
    asm volatile("s_waitcnt lgkmcnt(0)\n\ts_barrier" ::: "memory");
}

// ---------------- K1: Pc[kc][j][t] = M[kc*32+t][j], M = Wq^T Wk  (bf16)
// plus Wv -> bf16 copy.
__global__ __launch_bounds__(256) void prep_kernel(
    const float* __restrict__ Wq, const float* __restrict__ Wk,
    const float* __restrict__ Wv, unsigned short* __restrict__ Pc,
    unsigned short* __restrict__ Wvb)
{
    int b = blockIdx.x;
    if (b < 1024) {
        int j0 = (b >> 4) * 8;
        int kc = b & 15;
        int jloc = threadIdx.x >> 5;
        int t = threadIdx.x & 31;
        int j = j0 + jloc, d = kc * 32 + t;
        float acc = 0.f;
        #pragma unroll 8
        for (int e = 0; e < 512; ++e)
            acc = fmaf(Wk[e * 512 + j], Wq[e * 512 + d], acc);
        Pc[((kc * 512) + j) * 32 + t] = f2bf(acc);
    } else {
        int i = (b - 1024) * 256 + (int)threadIdx.x;
        Wvb[i] = f2bf(Wv[i]);
    }
}

// issue H column-quarter q (32-row tile): 2 float4/thread.
__device__ __forceinline__ void issue_q32(int q, int tid, const float4* hsrc, float4 (&hq)[2]) {
    #pragma unroll
    for (int r = 0; r < 2; ++r) {
        int flat = r * 512 + tid;          // [0,1024)
        hq[r] = hsrc[(flat >> 5) * 128 + q * 32 + (flat & 31)];
    }
}

// convert quarter q -> bf16 swizzled HBF (consumes hq)
__device__ __forceinline__ void convert_q32(int q, int tid, char* HBF, float4 (&hq)[2]) {
    #pragma unroll
    for (int r = 0; r < 2; ++r) {
        int flat = r * 512 + tid;
        int row = flat >> 5, ch = flat & 31;
        ushort4 bv;
        bv.x = f2bf(hq[r].x); bv.y = f2bf(hq[r].y);
        bv.z = f2bf(hq[r].z); bv.w = f2bf(hq[r].w);
        *(ushort4*)(HBF + swz1k((unsigned)row * 1024u + (unsigned)(q * 32 + ch) * 8u)) = bv;
    }
}

// GEMM over kc = kcbase..kcbase+3 with 2-deep rolling Pc prefetch.
// If PREF: at k==1, AFTER that iteration's Pc issue (kcbase+3), issue the H
// quarter. Consume-order proof: Pc(kcbase+3) is consumed at k==3 and was
// issued BEFORE the H quarter (so its wait leaves H in flight); the first
// Pc consumed after H (kcbase+4) is consumed only in the NEXT gemm call,
// which runs after convert() has already waited on H. No forced drains.
template<bool PREF>
__device__ __forceinline__ void gemm_q32(
    int kcbase, int tid, int rl, int kg,
    const unsigned short* bptr, char* HBF,
    bf16x8 (&st0)[4], bf16x8 (&st1)[4],
    f32x4 (&acc)[2][4],
    float4 (&hq)[2], const float4* hsrc, int hq_q)
{
    #pragma unroll
    for (int k = 0; k < 4; ++k) {
        const int kc = kcbase + k;
        bf16x8 bn[4];
        if (kc + 2 < 16) {
            #pragma unroll
            for (int jj = 0; jj < 4; ++jj)
                bn[jj] = *(const bf16x8*)(bptr + (kc + 2) * 16384 + jj * 512);
        }
        if (PREF && k == 1) {
            __builtin_amdgcn_sched_barrier(0);
            issue_q32(hq_q, tid, hsrc, hq);
            __builtin_amdgcn_sched_barrier(0);
        }
        bf16x8 a[2];
        #pragma unroll
        for (int i = 0; i < 2; ++i) {
            unsigned off = (unsigned)(i * 16 + rl) * 1024u + (unsigned)kc * 64u + (unsigned)kg * 16u;
            a[i] = *(bf16x8*)(HBF + swz1k(off));
        }
        #pragma unroll
        for (int i = 0; i < 2; ++i)
            #pragma unroll
            for (int jj = 0; jj < 4; ++jj)
                acc[i][jj] = __builtin_amdgcn_mfma_f32_16x16x32_bf16(a[i], st0[jj], acc[i][jj], 0, 0, 0);
        #pragma unroll
        for (int jj = 0; jj < 4; ++jj) { st0[jj] = st1[jj]; st1[jj] = bn[jj]; }
    }
}

// ---------------- K2: fused main kernel. 1 block = 2 batches = 32 H rows.
// LDS 66 KB -> 2 blocks/CU; quarter-pipelined H staging, 2-deep Pc prefetch,
// raw lgkm-only barriers (no vmcnt drains anywhere).
__global__ __launch_bounds__(512, 4) void attn_main_kernel(
    const float* __restrict__ H, const float* __restrict__ F,
    const unsigned short* __restrict__ Pc,
    float* __restrict__ out, unsigned short* __restrict__ g_ws)
{
    extern __shared__ char smem[];
    char* HBF  = smem;                        // 32 rows x 1024B, swizzled (32 KB)
    char* TBF  = smem + 32768;                // 32 KB
    float* wbuf = (float*)(smem + 65536);     // [2][16]
    float* FL   = (float*)(smem + 65664);     // [32]
    float* LFL  = (float*)(smem + 65792);     // [32]

    const int tid = threadIdx.x;
    const int wv = tid >> 6;
    const int ln = tid & 63;
    const int rl = ln & 15;
    const int kg = ln >> 4;
    const int blk = blockIdx.x;
    const long long gr0 = (long long)blk * 32;
    const float4* hsrc = (const float4*)(H + gr0 * 512);

    float fval = 0.f;
    if (tid < 32) fval = F[blk * 32 + tid];

    float4 hqA[2], hqB[2];
    issue_q32(0, tid, hsrc, hqA);

    const unsigned short* bptr = Pc + ((wv * 64 + rl) * 32 + kg * 8);
    bf16x8 st0[4], st1[4];
    #pragma unroll
    for (int jj = 0; jj < 4; ++jj) st0[jj] = *(const bf16x8*)(bptr + 0 * 16384 + jj * 512);
    #pragma unroll
    for (int jj = 0; jj < 4; ++jj) st1[jj] = *(const bf16x8*)(bptr + 1 * 16384 + jj * 512);

    issue_q32(1, tid, hsrc, hqB);

    if (tid < 32) {
        FL[tid] = fval;
        LFL[tid] = logf(fval + 1e-8f);
    }

    f32x4 acc[2][4];
    #pragma unroll
    for (int i = 0; i < 2; ++i)
        #pragma unroll
        for (int jj = 0; jj < 4; ++jj)
            acc[i][jj] = f32x4{0.f, 0.f, 0.f, 0.f};

    convert_q32(0, tid, HBF, hqA);
    bar_lgkm();
    gemm_q32<true >(0,  tid, rl, kg, bptr, HBF, st0, st1, acc, hqA, hsrc, 2);
    convert_q32(1, tid, HBF, hqB);
    bar_lgkm();
    gemm_q32<true >(4,  tid, rl, kg, bptr, HBF, st0, st1, acc, hqB, hsrc, 3);
    convert_q32(2, tid, HBF, hqA);
    bar_lgkm();
    gemm_q32<false>(8,  tid, rl, kg, bptr, HBF, st0, st1, acc, hqA, hsrc, 0);
    convert_q32(3, tid, HBF, hqB);
    bar_lgkm();
    gemm_q32<false>(12, tid, rl, kg, bptr, HBF, st0, st1, acc, hqB, hsrc, 0);

    // write T into TBF (C layout: col=lane&15, row=(lane>>4)*4+p)
    #pragma unroll
    for (int i = 0; i < 2; ++i)
        #pragma unroll
        for (int jj = 0; jj < 4; ++jj)
            #pragma unroll
            for (int p = 0; p < 4; ++p) {
                unsigned row = (unsigned)(i * 16 + kg * 4 + p);
                unsigned col = (unsigned)(wv * 64 + jj * 16 + rl);
                *(unsigned short*)(TBF + swz1k(row * 1024u + col * 2u)) = f2bf(acc[i][jj][p]);
            }
    bar_lgkm();   // TBF ready

    // ---- phase 3: waves 0-1: scores+softmax+w ; waves 2-5: residual pool
    if (wv < 2) {
        f32x4 sc0 = f32x4{0.f,0.f,0.f,0.f}, sc1 = sc0, sc2 = sc0, sc3 = sc0;
        __builtin_amdgcn_s_setprio(1);
        #pragma unroll
        for (int kc = 0; kc < 16; ++kc) {
            unsigned off = (unsigned)(wv * 16 + rl) * 1024u + (unsigned)kc * 64u + (unsigned)kg * 16u;
            bf16x8 aT = *(bf16x8*)(TBF + swz1k(off));
            bf16x8 bH = *(bf16x8*)(HBF + swz1k(off));   // H rows as B == H^T
            if ((kc & 3) == 0) sc0 = __builtin_amdgcn_mfma_f32_16x16x32_bf16(aT, bH, sc0, 0, 0, 0);
            else if ((kc & 3) == 1) sc1 = __builtin_amdgcn_mfma_f32_16x16x32_bf16(aT, bH, sc1, 0, 0, 0);
            else if ((kc & 3) == 2) sc2 = __builtin_amdgcn_mfma_f32_16x16x32_bf16(aT, bH, sc2, 0, 0, 0);
            else sc3 = __builtin_amdgcn_mfma_f32_16x16x32_bf16(aT, bH, sc3, 0, 0, 0);
        }
        __builtin_amdgcn_s_setprio(0);
        f32x4 sc;
        #pragma unroll
        for (int p = 0; p < 4; ++p) sc[p] = (sc0[p] + sc1[p]) + (sc2[p] + sc3[p]);

        float bias = LFL[wv * 16 + rl];
        float alpha[4];
        #pragma unroll
        for (int p = 0; p < 4; ++p) {
            float s = sc[p] * 0.044194173824159216f + bias;  // 1/sqrt(512)
            float m = s;
            m = fmaxf(m, __shfl_xor(m, 8));
            m = fmaxf(m, __shfl_xor(m, 4));
            m = fmaxf(m, __shfl_xor(m, 2));
            m = fmaxf(m, __shfl_xor(m, 1));
            float e = expf(s - m);
            float sum = e;
            sum += __shfl_xor(sum, 8);
            sum += __shfl_xor(sum, 4);
            sum += __shfl_xor(sum, 2);
            sum += __shfl_xor(sum, 1);
            alpha[p] = e / sum;
        }
        float part = 0.f;
        #pragma unroll
        for (int p = 0; p < 4; ++p) part += FL[wv * 16 + kg * 4 + p] * alpha[p];
        part += __shfl_xor(part, 16);
        part += __shfl_xor(part, 32);
        if (ln < 16) wbuf[wv * 16 + ln] = part;
    } else if (wv < 6) {
        // residual F-pool: unit = (batch bb, d-half dh); lane covers 4 d
        int u = wv - 2;
        int bb = u >> 1, dh = u & 1;
        const long long Bg = (long long)blk * 2 + bb;
        int d0 = dh * 256 + ln * 4;
        float o[4];
        #pragma unroll
        for (int q = 0; q < 4; ++q) o[q] = 0.f;
        #pragma unroll
        for (int k = 0; k < 16; ++k) {
            unsigned off = (unsigned)(bb * 16 + k) * 1024u + (unsigned)d0 * 2u;
            ushort4 h = *(ushort4*)(HBF + swz1k(off));
            float fk = FL[bb * 16 + k];
            o[0] = fmaf(fk, bf2f(h.x), o[0]); o[1] = fmaf(fk, bf2f(h.y), o[1]);
            o[2] = fmaf(fk, bf2f(h.z), o[2]); o[3] = fmaf(fk, bf2f(h.w), o[3]);
        }
        float4 oa; oa.x = o[0]; oa.y = o[1]; oa.z = o[2]; oa.w = o[3];
        *(float4*)(out + Bg * 512 + d0) = oa;
    }
    bar_lgkm();   // wbuf ready

    // ---- phase 4: g (bf16). 8 waves = 2 batches x 4 d-quarters, from LDS.
    {
        int bb = wv >> 2, q4 = wv & 3;
        const long long Bg = (long long)blk * 2 + bb;
        int d0 = q4 * 128 + ln * 2;
        float g0 = 0.f, g1 = 0.f;
        #pragma unroll
        for (int k = 0; k < 16; ++k) {
            unsigned off = (unsigned)(bb * 16 + k) * 1024u + (unsigned)d0 * 2u;
            ushort2 h = *(ushort2*)(HBF + swz1k(off));
            float wk = wbuf[bb * 16 + k];
            g0 = fmaf(wk, bf2f(h.x), g0); g1 = fmaf(wk, bf2f(h.y), g1);
        }
        ushort2 g2; g2.x = f2bf(g0); g2.y = f2bf(g1);
        *(ushort2*)(g_ws + Bg * 512 + d0) = g2;
    }
}

// ---------------- K3: out += g @ Wv^T   (8192x512 @ 512x512, bf16 MFMA)
__global__ __launch_bounds__(256) void out_gemm_kernel(
    const unsigned short* __restrict__ g_ws,
    const unsigned short* __restrict__ Wvb,
    float* __restrict__ out)
{
    extern __shared__ char smem[];  // 32 KB: 32 rows x 1024B, swizzled
    const int tid = threadIdx.x;
    const int wv = tid >> 6, ln = tid & 63;
    const int rl = ln & 15, kg = ln >> 4;
    const long long r0 = (long long)blockIdx.x * 32;
    {
        const uint4* src = (const uint4*)(g_ws + r0 * 512);
        #pragma unroll
        for (int q = 0; q < 8; ++q) {
            int idx = q * 256 + tid;
            *(uint4*)(smem + swz1k((unsigned)idx * 16u)) = src[idx];
        }
    }
    __syncthreads();
    f32x4 acc[2][8];
    #pragma unroll
    for (int i = 0; i < 2; ++i)
        #pragma unroll
        for (int jj = 0; jj < 8; ++jj)
            acc[i][jj] = f32x4{0.f, 0.f, 0.f, 0.f};
    for (int kc = 0; kc < 16; ++kc) {
        bf16x8 a[2];
        #pragma unroll
        for (int i = 0; i < 2; ++i) {
            unsigned off = (unsigned)(i * 16 + rl) * 1024u + (unsigned)kc * 64u + (unsigned)kg * 16u;
            a[i] = *(bf16x8*)(smem + swz1k(off));
        }
        bf16x8 bfr[8];
        #pragma unroll
        for (int jj = 0; jj < 8; ++jj) {
            int n = wv * 128 + jj * 16 + rl;
            bfr[jj] = *(const bf16x8*)(Wvb + n * 512 + kc * 32 + kg * 8);
        }
        #pragma unroll
        for (int i = 0; i < 2; ++i)
            #pragma unroll
            for (int jj = 0; jj < 8; ++jj)
                acc[i][jj] = __builtin_amdgcn_mfma_f32_16x16x32_bf16(a[i], bfr[jj], acc[i][jj], 0, 0, 0);
    }
    #pragma unroll
    for (int i = 0; i < 2; ++i)
        #pragma unroll
        for (int jj = 0; jj < 8; ++jj)
            #pragma unroll
            for (int p = 0; p < 4; ++p) {
                int row = i * 16 + kg * 4 + p;
                int col = wv * 128 + jj * 16 + rl;
                out[(r0 + row) * 512 + col] += acc[i][jj][p];
            }
}

extern "C" void kernel_launch(void* const* d_in, const int* in_sizes, int n_in,
                              void* d_out, int out_size, void* d_ws, size_t ws_size,
                              hipStream_t stream)
{
    const float* H  = (const float*)d_in[0];
    const float* F  = (const float*)d_in[1];
    const float* Wq = (const float*)d_in[2];
    const float* Wk = (const float*)d_in[3];
    const float* Wv = (const float*)d_in[4];
    float* out = (float*)d_out;

    unsigned short* Pc  = (unsigned short*)d_ws;       // 16*512*32   = 262144 bf16
    unsigned short* Wvb = Pc + 262144;                 // 512*512     = 262144 bf16
    unsigned short* g   = Wvb + 262144;                // 8192*512    = 4194304 bf16
    (void)in_sizes; (void)n_in; (void)out_size; (void)ws_size;

    prep_kernel<<<dim3(2048), dim3(256), 0, stream>>>(Wq, Wk, Wv, Pc, Wvb);
    attn_main_kernel<<<dim3(4096), dim3(512), 65920, stream>>>(H, F, Pc, out, g);
    out_gemm_kernel<<<dim3(256), dim3(256), 32768, stream>>>(g, Wvb, out);
}

// Round 11
// 196.288 us; speedup vs baseline: 1.9961x; 1.0987x over previous
//
#include <hip/hip_runtime.h>

typedef __bf16 bf16x8 __attribute__((ext_vector_type(8)));
typedef float f32x4 __attribute__((ext_vector_type(4)));

__device__ __forceinline__ unsigned short f2bf(float f) {
    unsigned int u = __builtin_bit_cast(unsigned int, f);
    u += 0x7fffu + ((u >> 16) & 1u);
    return (unsigned short)(u >> 16);
}
__device__ __forceinline__ float bf2f(unsigned short u) {
    return __builtin_bit_cast(float, (unsigned)u << 16);
}

// XOR swizzle for 1024B-row LDS tiles: byte ^= ((row&7)<<4)
__device__ __forceinline__ unsigned swz1k(unsigned byte) {
    return byte ^ ((byte >> 6) & 0x70u);
}

// Raw barrier: LDS-visibility only; does NOT drain vmcnt.
__device__ __forceinline__ void bar_lgkm() {
    asm volatile("s_waitcnt lgkmcnt(0)\n\ts_barrier" ::: "memory");
}

// ---------------- K1: Pc[kc][j][t] = M[kc*32+t][j], M = Wq^T Wk  (bf16)
// plus Wv -> bf16 copy.
__global__ __launch_bounds__(256) void prep_kernel(
    const float* __restrict__ Wq, const float* __restrict__ Wk,
    const float* __restrict__ Wv, unsigned short* __restrict__ Pc,
    unsigned short* __restrict__ Wvb)
{
    int b = blockIdx.x;
    if (b < 1024) {
        int j0 = (b >> 4) * 8;
        int kc = b & 15;
        int jloc = threadIdx.x >> 5;
        int t = threadIdx.x & 31;
        int j = j0 + jloc, d = kc * 32 + t;
        float acc = 0.f;
        #pragma unroll 8
        for (int e = 0; e < 512; ++e)
            acc = fmaf(Wk[e * 512 + j], Wq[e * 512 + d], acc);
        Pc[((kc * 512) + j) * 32 + t] = f2bf(acc);
    } else {
        int i = (b - 1024) * 256 + (int)threadIdx.x;
        Wvb[i] = f2bf(Wv[i]);
    }
}

// issue H column-quarter q (64-row tile, 1024 threads): 2 float4/thread.
__device__ __forceinline__ void issue_q(int q, int tid, const float4* hsrc, float4 (&hq)[2]) {
    #pragma unroll
    for (int r = 0; r < 2; ++r) {
        int flat = r * 1024 + tid;         // [0,2048)
        hq[r] = hsrc[(flat >> 5) * 128 + q * 32 + (flat & 31)];
    }
}

// convert quarter q -> bf16 swizzled HBF (consumes hq)
__device__ __forceinline__ void convert_q(int q, int tid, char* HBF, float4 (&hq)[2]) {
    #pragma unroll
    for (int r = 0; r < 2; ++r) {
        int flat = r * 1024 + tid;
        int row = flat >> 5, ch = flat & 31;
        ushort4 bv;
        bv.x = f2bf(hq[r].x); bv.y = f2bf(hq[r].y);
        bv.z = f2bf(hq[r].z); bv.w = f2bf(hq[r].w);
        *(ushort4*)(HBF + swz1k((unsigned)row * 1024u + (unsigned)(q * 32 + ch) * 8u)) = bv;
    }
}

// GEMM over kc = kcbase..kcbase+3, 2-deep rolling Pc prefetch, per-wave
// j-slice of 32 cols (2 frags). If PREF: issue H quarter at k==1 AFTER that
// iter's Pc issue (consume-order safe: the Pc group issued before H is the
// last one consumed before the next convert's H wait).
template<bool PREF>
__device__ __forceinline__ void gemm_q(
    int kcbase, int tid, int rl, int kg,
    const unsigned short* bptr, char* HBF,
    bf16x8 (&st0)[2], bf16x8 (&st1)[2],
    f32x4 (&acc)[4][2],
    float4 (&hq)[2], const float4* hsrc, int hq_q)
{
    #pragma unroll
    for (int k = 0; k < 4; ++k) {
        const int kc = kcbase + k;
        bf16x8 bn[2];
        if (kc + 2 < 16) {
            #pragma unroll
            for (int jj = 0; jj < 2; ++jj)
                bn[jj] = *(const bf16x8*)(bptr + (kc + 2) * 16384 + jj * 512);
        }
        if (PREF && k == 1) {
            __builtin_amdgcn_sched_barrier(0);
            issue_q(hq_q, tid, hsrc, hq);
            __builtin_amdgcn_sched_barrier(0);
        }
        bf16x8 a[4];
        #pragma unroll
        for (int i = 0; i < 4; ++i) {
            unsigned off = (unsigned)(i * 16 + rl) * 1024u + (unsigned)kc * 64u + (unsigned)kg * 16u;
            a[i] = *(bf16x8*)(HBF + swz1k(off));
        }
        #pragma unroll
        for (int i = 0; i < 4; ++i)
            #pragma unroll
            for (int jj = 0; jj < 2; ++jj)
                acc[i][jj] = __builtin_amdgcn_mfma_f32_16x16x32_bf16(a[i], st0[jj], acc[i][jj], 0, 0, 0);
        #pragma unroll
        for (int jj = 0; jj < 2; ++jj) { st0[jj] = st1[jj]; st1[jj] = bn[jj]; }
    }
}

// ---------------- K2: fused main kernel. 1 block = 4 batches = 64 H rows,
// 1024 threads (16 waves -> 4 waves/SIMD). Same traffic as the 512-thread
// 64-row version; 2x the latency hiding. Quarter-pipelined H, 2-deep Pc,
// raw lgkm-only barriers.
__global__ __launch_bounds__(1024, 4) void attn_main_kernel(
    const float* __restrict__ H, const float* __restrict__ F,
    const unsigned short* __restrict__ Pc,
    float* __restrict__ out, unsigned short* __restrict__ g_ws)
{
    extern __shared__ char smem[];
    char* HBF  = smem;                        // 64 rows x 1024B, swizzled (64 KB)
    char* TBF  = smem + 65536;                // 64 KB
    float* wbuf = (float*)(smem + 131072);    // [4][16]
    float* FL   = (float*)(smem + 131328);    // [64]
    float* LFL  = (float*)(smem + 131584);    // [64]

    const int tid = threadIdx.x;
    const int wv = tid >> 6;                  // 0..15
    const int ln = tid & 63;
    const int rl = ln & 15;
    const int kg = ln >> 4;
    const int blk = blockIdx.x;
    const long long gr0 = (long long)blk * 64;
    const float4* hsrc = (const float4*)(H + gr0 * 512);

    float fval = 0.f;
    if (tid < 64) fval = F[blk * 64 + tid];

    float4 hqA[2], hqB[2];
    issue_q(0, tid, hsrc, hqA);

    // per-wave j-slice: j = wv*32 + jj*16 + rl, jj in {0,1}
    const unsigned short* bptr = Pc + ((wv * 32 + rl) * 32 + kg * 8);
    bf16x8 st0[2], st1[2];
    #pragma unroll
    for (int jj = 0; jj < 2; ++jj) st0[jj] = *(const bf16x8*)(bptr + 0 * 16384 + jj * 512);
    #pragma unroll
    for (int jj = 0; jj < 2; ++jj) st1[jj] = *(const bf16x8*)(bptr + 1 * 16384 + jj * 512);

    issue_q(1, tid, hsrc, hqB);

    if (tid < 64) {
        FL[tid] = fval;
        LFL[tid] = logf(fval + 1e-8f);
    }

    f32x4 acc[4][2];
    #pragma unroll
    for (int i = 0; i < 4; ++i)
        #pragma unroll
        for (int jj = 0; jj < 2; ++jj)
            acc[i][jj] = f32x4{0.f, 0.f, 0.f, 0.f};

    convert_q(0, tid, HBF, hqA);
    bar_lgkm();
    gemm_q<true >(0,  tid, rl, kg, bptr, HBF, st0, st1, acc, hqA, hsrc, 2);
    convert_q(1, tid, HBF, hqB);
    bar_lgkm();
    gemm_q<true >(4,  tid, rl, kg, bptr, HBF, st0, st1, acc, hqB, hsrc, 3);
    convert_q(2, tid, HBF, hqA);
    bar_lgkm();
    gemm_q<false>(8,  tid, rl, kg, bptr, HBF, st0, st1, acc, hqA, hsrc, 0);
    convert_q(3, tid, HBF, hqB);
    bar_lgkm();
    gemm_q<false>(12, tid, rl, kg, bptr, HBF, st0, st1, acc, hqB, hsrc, 0);

    // write T into TBF (C layout: col=lane&15, row=(lane>>4)*4+p)
    #pragma unroll
    for (int i = 0; i < 4; ++i)
        #pragma unroll
        for (int jj = 0; jj < 2; ++jj)
            #pragma unroll
            for (int p = 0; p < 4; ++p) {
                unsigned row = (unsigned)(i * 16 + kg * 4 + p);
                unsigned col = (unsigned)(wv * 32 + jj * 16 + rl);
                *(unsigned short*)(TBF + swz1k(row * 1024u + col * 2u)) = f2bf(acc[i][jj][p]);
            }
    bar_lgkm();   // TBF ready

    // ---- phase 3: waves 0-3: scores+softmax+w ; waves 4-11: residual pool
    if (wv < 4) {
        f32x4 sc0 = f32x4{0.f,0.f,0.f,0.f}, sc1 = sc0, sc2 = sc0, sc3 = sc0;
        __builtin_amdgcn_s_setprio(1);
        #pragma unroll
        for (int kc = 0; kc < 16; ++kc) {
            unsigned off = (unsigned)(wv * 16 + rl) * 1024u + (unsigned)kc * 64u + (unsigned)kg * 16u;
            bf16x8 aT = *(bf16x8*)(TBF + swz1k(off));
            bf16x8 bH = *(bf16x8*)(HBF + swz1k(off));   // H rows as B == H^T
            if ((kc & 3) == 0) sc0 = __builtin_amdgcn_mfma_f32_16x16x32_bf16(aT, bH, sc0, 0, 0, 0);
            else if ((kc & 3) == 1) sc1 = __builtin_amdgcn_mfma_f32_16x16x32_bf16(aT, bH, sc1, 0, 0, 0);
            else if ((kc & 3) == 2) sc2 = __builtin_amdgcn_mfma_f32_16x16x32_bf16(aT, bH, sc2, 0, 0, 0);
            else sc3 = __builtin_amdgcn_mfma_f32_16x16x32_bf16(aT, bH, sc3, 0, 0, 0);
        }
        __builtin_amdgcn_s_setprio(0);
        f32x4 sc;
        #pragma unroll
        for (int p = 0; p < 4; ++p) sc[p] = (sc0[p] + sc1[p]) + (sc2[p] + sc3[p]);

        float bias = LFL[wv * 16 + rl];
        float alpha[4];
        #pragma unroll
        for (int p = 0; p < 4; ++p) {
            float s = sc[p] * 0.044194173824159216f + bias;  // 1/sqrt(512)
            float m = s;
            m = fmaxf(m, __shfl_xor(m, 8));
            m = fmaxf(m, __shfl_xor(m, 4));
            m = fmaxf(m, __shfl_xor(m, 2));
            m = fmaxf(m, __shfl_xor(m, 1));
            float e = expf(s - m);
            float sum = e;
            sum += __shfl_xor(sum, 8);
            sum += __shfl_xor(sum, 4);
            sum += __shfl_xor(sum, 2);
            sum += __shfl_xor(sum, 1);
            alpha[p] = e / sum;
        }
        float part = 0.f;
        #pragma unroll
        for (int p = 0; p < 4; ++p) part += FL[wv * 16 + kg * 4 + p] * alpha[p];
        part += __shfl_xor(part, 16);
        part += __shfl_xor(part, 32);
        if (ln < 16) wbuf[wv * 16 + ln] = part;
    } else if (wv < 12) {
        // residual F-pool: unit = (batch bb, d-half dh); lane covers 4 d
        int u = wv - 4;
        int bb = u >> 1, dh = u & 1;
        const long long Bg = (long long)blk * 4 + bb;
        int d0 = dh * 256 + ln * 4;
        float o[4];
        #pragma unroll
        for (int q = 0; q < 4; ++q) o[q] = 0.f;
        #pragma unroll
        for (int k = 0; k < 16; ++k) {
            unsigned off = (unsigned)(bb * 16 + k) * 1024u + (unsigned)d0 * 2u;
            ushort4 h = *(ushort4*)(HBF + swz1k(off));
            float fk = FL[bb * 16 + k];
            o[0] = fmaf(fk, bf2f(h.x), o[0]); o[1] = fmaf(fk, bf2f(h.y), o[1]);
            o[2] = fmaf(fk, bf2f(h.z), o[2]); o[3] = fmaf(fk, bf2f(h.w), o[3]);
        }
        float4 oa; oa.x = o[0]; oa.y = o[1]; oa.z = o[2]; oa.w = o[3];
        *(float4*)(out + Bg * 512 + d0) = oa;
    }
    bar_lgkm();   // wbuf ready

    // ---- phase 4: g (bf16). 16 waves = 4 batches x 4 d-quarters, from LDS.
    {
        int bb = wv >> 2, q4 = wv & 3;
        const long long Bg = (long long)blk * 4 + bb;
        int d0 = q4 * 128 + ln * 2;
        float g0 = 0.f, g1 = 0.f;
        #pragma unroll
        for (int k = 0; k < 16; ++k) {
            unsigned off = (unsigned)(bb * 16 + k) * 1024u + (unsigned)d0 * 2u;
            ushort2 h = *(ushort2*)(HBF + swz1k(off));
            float wk = wbuf[bb * 16 + k];
            g0 = fmaf(wk, bf2f(h.x), g0); g1 = fmaf(wk, bf2f(h.y), g1);
        }
        ushort2 g2; g2.x = f2bf(g0); g2.y = f2bf(g1);
        *(ushort2*)(g_ws + Bg * 512 + d0) = g2;
    }
}

// ---------------- K3: out += g @ Wv^T   (8192x512 @ 512x512, bf16 MFMA)
__global__ __launch_bounds__(256) void out_gemm_kernel(
    const unsigned short* __restrict__ g_ws,
    const unsigned short* __restrict__ Wvb,
    float* __restrict__ out)
{
    extern __shared__ char smem[];  // 32 KB: 32 rows x 1024B, swizzled
    const int tid = threadIdx.x;
    const int wv = tid >> 6, ln = tid & 63;
    const int rl = ln & 15, kg = ln >> 4;
    const long long r0 = (long long)blockIdx.x * 32;
    {
        const uint4* src = (const uint4*)(g_ws + r0 * 512);
        #pragma unroll
        for (int q = 0; q < 8; ++q) {
            int idx = q * 256 + tid;
            *(uint4*)(smem + swz1k((unsigned)idx * 16u)) = src[idx];
        }
    }
    __syncthreads();
    f32x4 acc[2][8];
    #pragma unroll
    for (int i = 0; i < 2; ++i)
        #pragma unroll
        for (int jj = 0; jj < 8; ++jj)
            acc[i][jj] = f32x4{0.f, 0.f, 0.f, 0.f};
    for (int kc = 0; kc < 16; ++kc) {
        bf16x8 a[2];
        #pragma unroll
        for (int i = 0; i < 2; ++i) {
            unsigned off = (unsigned)(i * 16 + rl) * 1024u + (unsigned)kc * 64u + (unsigned)kg * 16u;
            a[i] = *(bf16x8*)(smem + swz1k(off));
        }
        bf16x8 bfr[8];
        #pragma unroll
        for (int jj = 0; jj < 8; ++jj) {
            int n = wv * 128 + jj * 16 + rl;
            bfr[jj] = *(const bf16x8*)(Wvb + n * 512 + kc * 32 + kg * 8);
        }
        #pragma unroll
        for (int i = 0; i < 2; ++i)
            #pragma unroll
            for (int jj = 0; jj < 8; ++jj)
                acc[i][jj] = __builtin_amdgcn_mfma_f32_16x16x32_bf16(a[i], bfr[jj], acc[i][jj], 0, 0, 0);
    }
    #pragma unroll
    for (int i = 0; i < 2; ++i)
        #pragma unroll
        for (int jj = 0; jj < 8; ++jj)
            #pragma unroll
            for (int p = 0; p < 4; ++p) {
                int row = i * 16 + kg * 4 + p;
                int col = wv * 128 + jj * 16 + rl;
                out[(r0 + row) * 512 + col] += acc[i][jj][p];
            }
}

extern "C" void kernel_launch(void* const* d_in, const int* in_sizes, int n_in,
                              void* d_out, int out_size, void* d_ws, size_t ws_size,
                              hipStream_t stream)
{
    const float* H  = (const float*)d_in[0];
    const float* F  = (const float*)d_in[1];
    const float* Wq = (const float*)d_in[2];
    const float* Wk = (const float*)d_in[3];
    const float* Wv = (const float*)d_in[4];
    float* out = (float*)d_out;

    unsigned short* Pc  = (unsigned short*)d_ws;       // 16*512*32   = 262144 bf16
    unsigned short* Wvb = Pc + 262144;                 // 512*512     = 262144 bf16
    unsigned short* g   = Wvb + 262144;                // 8192*512    = 4194304 bf16
    (void)in_sizes; (void)n_in; (void)out_size; (void)ws_size;

    prep_kernel<<<dim3(2048), dim3(256), 0, stream>>>(Wq, Wk, Wv, Pc, Wvb);
    attn_main_kernel<<<dim3(2048), dim3(1024), 131840, stream>>>(H, F, Pc, out, g);
    out_gemm_kernel<<<dim3(256), dim3(256), 32768, stream>>>(g, Wvb, out);
}